// Round 7
// baseline (289.706 us; speedup 1.0000x reference)
//
#include <hip/hip_runtime.h>
#include <math.h>

#define BATCH 4
#define SEQ   4096
#define DM    128
#define TOPK  64
#define SCALE 0.08838834764831845f   // 1/sqrt(128)
#define CAP   384                    // candidate buffer per row

typedef short bf16x8 __attribute__((ext_vector_type(8)));
typedef float f32x4  __attribute__((ext_vector_type(4)));

// ---- bf16 helpers (RNE) ----
__device__ __forceinline__ unsigned short f2bf(float x) {
    unsigned u = __float_as_uint(x);
    u += 0x7FFFu + ((u >> 16) & 1u);
    return (unsigned short)(u >> 16);
}
__device__ __forceinline__ float bf2f(unsigned short h) {
    return __uint_as_float(((unsigned)h) << 16);
}
__device__ __forceinline__ void split3(float x, unsigned short& h,
                                       unsigned short& md, unsigned short& l) {
    h = f2bf(x);
    float r1 = x - bf2f(h);
    md = f2bf(r1);
    float r2 = r1 - bf2f(md);
    l = f2bf(r2);
}

__device__ __forceinline__ unsigned fmap(float f) {
    unsigned u = __float_as_uint(f);
    return (u & 0x80000000u) ? ~u : (u | 0x80000000u);
}
__device__ __forceinline__ float finv(unsigned u) {
    return (u & 0x80000000u) ? __uint_as_float(u & 0x7FFFFFFFu) : __uint_as_float(~u);
}
__device__ __forceinline__ float wave_fmax(float v) {
    #pragma unroll
    for (int m = 32; m; m >>= 1) v = fmaxf(v, __shfl_xor(v, m));
    return v;
}
__device__ __forceinline__ float wave_fsum(float v) {
    #pragma unroll
    for (int m = 32; m; m >>= 1) v += __shfl_xor(v, m);
    return v;
}
__device__ __forceinline__ int wave_isum(int v) {
    #pragma unroll
    for (int m = 32; m; m >>= 1) v += __shfl_xor(v, m);
    return v;
}
__device__ __forceinline__ unsigned wave_umax(unsigned v) {
    #pragma unroll
    for (int m = 32; m; m >>= 1) { unsigned o = __shfl_xor(v, m); v = (o > v) ? o : v; }
    return v;
}

// async global->LDS, 16 B per lane (dest = wave-uniform base, HW adds lane*16)
__device__ __forceinline__ void gld16(const void* g, void* l) {
    __builtin_amdgcn_global_load_lds(
        (const __attribute__((address_space(1))) unsigned int*)g,
        (__attribute__((address_space(3))) unsigned int*)l, 16, 0, 0);
}

// ---------- RoPE + 3-way bf16 decomposition (main path) ----------
__global__ void rope_decomp(const float* __restrict__ q, const float* __restrict__ k,
                            unsigned short* __restrict__ qh, unsigned short* __restrict__ qm,
                            unsigned short* __restrict__ ql, unsigned short* __restrict__ kh,
                            unsigned short* __restrict__ km, unsigned short* __restrict__ kl) {
    int idx = blockIdx.x * blockDim.x + threadIdx.x;
    const int total = BATCH * SEQ * (DM / 2);
    if (idx >= total) return;
    int i   = idx & 63;
    int pos = (idx >> 6) & (SEQ - 1);
    int b   = idx >> 18;
    float dv  = powf(10000.0f, (float)(2 * i) / (float)DM);
    float ang = (float)pos / dv;
    float sn, cs;
    sincosf(ang, &sn, &cs);
    size_t base = ((size_t)b * SEQ + pos) * DM + 2 * i;
    float qe = q[base], qo = q[base + 1];
    float ke = k[base], ko = k[base + 1];
    float q0 = (qe * cs - qo * sn) * SCALE, q1 = (qe * sn + qo * cs) * SCALE;
    float k0 = ke * cs - ko * sn,          k1 = ke * sn + ko * cs;
    unsigned short h, m2, l;
    split3(q0, h, m2, l); qh[base] = h;     qm[base] = m2;     ql[base] = l;
    split3(q1, h, m2, l); qh[base + 1] = h; qm[base + 1] = m2; ql[base + 1] = l;
    split3(k0, h, m2, l); kh[base] = h;     km[base] = m2;     kl[base] = l;
    split3(k1, h, m2, l); kh[base + 1] = h; km[base + 1] = m2; kl[base + 1] = l;
}

// ---------- Phase A: logits via bf16 MFMA, 128x128 tile, LDS-staged 6-term ----------
// LDS layout per plane: [128 rows][4 units of 16B], unit swizzled: slot = u ^ (row&3).
__launch_bounds__(256, 3)
__global__ void logits_mfma(const unsigned short* __restrict__ qh, const unsigned short* __restrict__ qm,
                            const unsigned short* __restrict__ ql, const unsigned short* __restrict__ kh,
                            const unsigned short* __restrict__ km, const unsigned short* __restrict__ kl,
                            float* __restrict__ lg, int r0, int m, int stride) {
    const int st = blockIdx.x, qt = blockIdx.y, b = blockIdx.z;
    const int Q0 = r0 + qt * 128, S0 = st * 128;
    if (S0 > Q0 + 127) return;                     // block fully above diagonal

    __shared__ short Asl[3][128 * 32];             // 24 KB (3 planes x 128 rows x 32 bf16)
    __shared__ short Bsl[3][128 * 32];             // 24 KB

    const int tid = threadIdx.x, lane = tid & 63, w = tid >> 6;
    const int wm = (w >> 1) * 64, wn = (w & 1) * 64;
    const bool active = (S0 + wn <= Q0 + wm + 63);

    const unsigned short* qp[3] = { qh, qm, ql };
    const unsigned short* kp[3] = { kh, km, kl };

    // per-lane pieces for staging: row-in-chunk, slot, swizzled source unit
    const int srow = lane >> 2;                 // 0..15
    const int sslot = lane & 3;                 // LDS 16B slot
    const int sunit = sslot ^ (srow & 3);       // global 16B unit (involution)

    // fragment read offsets (elements) within a plane: row*32 + (u^(row&3))*8
    const int frow_a = wm + (lane & 15);        // + i*16
    const int frow_b = wn + (lane & 15);        // + j*16
    const int fu     = lane >> 4;
    const int fswz   = (fu ^ (lane & 3)) * 8;   // row&3 == lane&3 (tiles are 16-aligned)

    f32x4 acc[4][4] = {};

    for (int kk = 0; kk < 4; ++kk) {
        const int d0 = kk * 32;
        // ---- stage 48 KB: 48 chunks of 1024 B (16 rows x 64 B), 12 per wave ----
        for (int c = w; c < 48; c += 4) {
            bool isA = (c < 24);
            int c2 = isA ? c : c - 24;
            int p = c2 >> 3, rowbase = (c2 & 7) << 4;
            int grow = (isA ? Q0 : S0) + rowbase + srow;
            const unsigned short* src = (isA ? qp[p] : kp[p]) +
                ((size_t)b * SEQ + grow) * DM + d0 + sunit * 8;
            short* dst = (isA ? &Asl[p][rowbase * 32] : &Bsl[p][rowbase * 32]);
            gld16(src, dst);
        }
        __syncthreads();

        if (active) {
            bf16x8 Ah[4], Bh[4];
            #pragma unroll
            for (int i = 0; i < 4; ++i) {
                Ah[i] = *(const bf16x8*)&Asl[0][(frow_a + i * 16) * 32 + fswz];
                Bh[i] = *(const bf16x8*)&Bsl[0][(frow_b + i * 16) * 32 + fswz];
            }
            #pragma unroll
            for (int i = 0; i < 4; ++i)
                #pragma unroll
                for (int j = 0; j < 4; ++j)
                    acc[i][j] = __builtin_amdgcn_mfma_f32_16x16x32_bf16(Ah[i], Bh[j], acc[i][j], 0, 0, 0);

            bf16x8 Am[4], Bm[4];
            #pragma unroll
            for (int i = 0; i < 4; ++i) {
                Am[i] = *(const bf16x8*)&Asl[1][(frow_a + i * 16) * 32 + fswz];
                Bm[i] = *(const bf16x8*)&Bsl[1][(frow_b + i * 16) * 32 + fswz];
            }
            #pragma unroll
            for (int i = 0; i < 4; ++i)
                #pragma unroll
                for (int j = 0; j < 4; ++j) {
                    f32x4 c = acc[i][j];
                    c = __builtin_amdgcn_mfma_f32_16x16x32_bf16(Ah[i], Bm[j], c, 0, 0, 0);
                    c = __builtin_amdgcn_mfma_f32_16x16x32_bf16(Am[i], Bh[j], c, 0, 0, 0);
                    c = __builtin_amdgcn_mfma_f32_16x16x32_bf16(Am[i], Bm[j], c, 0, 0, 0);
                    acc[i][j] = c;
                }

            bf16x8 Al2[4], Bl2[4];
            #pragma unroll
            for (int i = 0; i < 4; ++i) {
                Al2[i] = *(const bf16x8*)&Asl[2][(frow_a + i * 16) * 32 + fswz];
                Bl2[i] = *(const bf16x8*)&Bsl[2][(frow_b + i * 16) * 32 + fswz];
            }
            #pragma unroll
            for (int i = 0; i < 4; ++i)
                #pragma unroll
                for (int j = 0; j < 4; ++j) {
                    f32x4 c = acc[i][j];
                    c = __builtin_amdgcn_mfma_f32_16x16x32_bf16(Ah[i], Bl2[j], c, 0, 0, 0);
                    c = __builtin_amdgcn_mfma_f32_16x16x32_bf16(Al2[i], Bh[j], c, 0, 0, 0);
                    acc[i][j] = c;
                }
        }
        __syncthreads();
    }

    if (!active) return;
    // C/D layout (m89-verified): col = lane&15, row = (lane>>4)*4 + reg
    const int colb = lane & 15, rowb = (lane >> 4) * 4;
    #pragma unroll
    for (int i = 0; i < 4; ++i) {
        #pragma unroll
        for (int r = 0; r < 4; ++r) {
            int qrow = Q0 + wm + i * 16 + rowb + r;
            size_t base = ((size_t)(b * m + (qrow - r0))) * stride;
            #pragma unroll
            for (int j = 0; j < 4; ++j) {
                int col = S0 + wn + j * 16 + colb;
                if (col <= qrow) lg[base + col] = acc[i][j][r];
            }
        }
    }
}

// ---------- Phase B: one WAVE per row; single-pass append + exact rank ----------
__launch_bounds__(256)
__global__ void select_out2(const float* __restrict__ lg, const float* __restrict__ v,
                            float* __restrict__ out, int r0, int m, int stride) {
    __shared__ unsigned long long bufK[4][CAP];   // (fmap(val)<<32) | (SEQ - idx)
    __shared__ float sW[4][TOPK];
    __shared__ int   sI[4][TOPK];
    __shared__ int   cnt[4];

    const int w = threadIdx.x >> 6, lane = threadIdx.x & 63;
    const int x = blockIdx.x * 4 + w, b = blockIdx.y;
    if (x >= m) return;
    const int t = r0 + x, n = t + 1;
    const float* row = lg + ((size_t)(b * m + x)) * stride;
    const float4* row4 = (const float4*)row;
    const int nv4 = n >> 2, rem = n & 3;

    if (n <= TOPK) {
        float val = (lane < n) ? row[lane] : -3.0e38f;
        float M = wave_fmax(val);
        float wgt = (lane < n) ? expf(val - M) : 0.f;
        float S = wave_fsum(wgt);
        sW[w][lane] = wgt;
        float inv = 1.f / S;
        float a0 = 0.f, a1 = 0.f;
        for (int j = 0; j < n; ++j) {
            float wj = sW[w][j];
            size_t base = ((size_t)b * SEQ + j) * DM;
            a0 += wj * v[base + lane];
            a1 += wj * v[base + 64 + lane];
        }
        size_t ob = ((size_t)b * SEQ + t) * DM;
        out[ob + lane] = a0 * inv;
        out[ob + 64 + lane] = a1 * inv;
        return;
    }

    // target quantile (only used when n > CAP-32)
    float T, zt = 0.f;
    if (n <= CAP - 32) {
        T = -3.0e38f;                 // take all n (<= 352 <= CAP)
    } else {
        float p  = 128.f / (float)n;
        float tt = sqrtf(-2.f * logf(p));
        zt = tt - (2.30753f + 0.27061f * tt) / (1.f + 0.99229f * tt + 0.04481f * tt * tt);
        T = zt;                        // sigma ~= 1
    }

    // ---- optimistic single-pass append; retry (rare) with recalibrated T ----
    float Tlo = -3.3e38f, Thi = 3.3e38f;    // Tlo: too many there; Thi: too few
    int C = 0;
    unsigned um = 0u;
    for (int it = 0; it < 12; ++it) {
        if (lane == 0) cnt[w] = 0;
        unsigned lm = 0u;
        for (int i = lane; i < nv4; i += 64) {
            float4 r4 = row4[i];
            int s = i << 2;
            if (r4.x >= T) { unsigned u = fmap(r4.x); lm = u > lm ? u : lm; int p = atomicAdd(&cnt[w], 1); if (p < CAP) bufK[w][p] = ((unsigned long long)u << 32) | (unsigned)(SEQ - s); }
            if (r4.y >= T) { unsigned u = fmap(r4.y); lm = u > lm ? u : lm; int p = atomicAdd(&cnt[w], 1); if (p < CAP) bufK[w][p] = ((unsigned long long)u << 32) | (unsigned)(SEQ - (s + 1)); }
            if (r4.z >= T) { unsigned u = fmap(r4.z); lm = u > lm ? u : lm; int p = atomicAdd(&cnt[w], 1); if (p < CAP) bufK[w][p] = ((unsigned long long)u << 32) | (unsigned)(SEQ - (s + 2)); }
            if (r4.w >= T) { unsigned u = fmap(r4.w); lm = u > lm ? u : lm; int p = atomicAdd(&cnt[w], 1); if (p < CAP) bufK[w][p] = ((unsigned long long)u << 32) | (unsigned)(SEQ - (s + 3)); }
        }
        if (lane < rem) {
            float val = row[nv4 * 4 + lane];
            if (val >= T) { unsigned u = fmap(val); lm = u > lm ? u : lm; int p = atomicAdd(&cnt[w], 1); if (p < CAP) bufK[w][p] = ((unsigned long long)u << 32) | (unsigned)(SEQ - (nv4 * 4 + lane)); }
        }
        um = wave_umax(lm);
        C = cnt[w];                    // same-wave LDS ordering
        if (C >= TOPK && C <= CAP) break;

        if (C < TOPK) Thi = fminf(Thi, T); else Tlo = fmaxf(Tlo, T);
        float Tn; bool okc = false;
        float phat = (float)(C < 1 ? 1 : C) / (float)n;
        if (phat < 0.45f && T > 0.05f) {
            float th = sqrtf(-2.f * logf(phat));
            float zh = th - (2.30753f + 0.27061f * th) / (1.f + 0.99229f * th + 0.04481f * th * th);
            if (zh > 0.05f) { Tn = T * (zt / zh); okc = true; }
        }
        if (!okc || !(Tn > Tlo && Tn < Thi)) {
            if (Tlo > -3.2e38f && Thi < 3.2e38f) Tn = 0.5f * (Tlo + Thi);
            else if (C < TOPK)                   Tn = T - 0.5f;
            else                                 Tn = T + 0.4f;
        }
        T = Tn;
    }
    const float M = finv(um);
    int Cw = C; if (Cw > CAP) Cw = CAP;

    sW[w][lane] = 0.f; sI[w][lane] = 0;          // safety init (pathological C<64)

    // ---- exact rank: descending key order == (value desc, index asc) ----
    for (int c0 = lane; c0 < Cw; c0 += 64) {
        unsigned long long kc = bufK[w][c0];
        int r = 0;
        for (int j = 0; j < Cw; ++j) r += (bufK[w][j] > kc);
        if (r < TOPK) {
            sW[w][r] = expf(finv((unsigned)(kc >> 32)) - M);
            sI[w][r] = SEQ - (int)(kc & 0xFFFFFFFFu);
        }
    }

    float S = wave_fsum(sW[w][lane]);
    float inv = 1.f / S;

    float a0 = 0.f, a1 = 0.f;
    #pragma unroll 4
    for (int j = 0; j < TOPK; ++j) {
        float wj = sW[w][j];
        int idx = sI[w][j];
        size_t base = ((size_t)b * SEQ + idx) * DM;
        a0 += wj * v[base + lane];
        a1 += wj * v[base + 64 + lane];
    }
    size_t ob = ((size_t)b * SEQ + t) * DM;
    out[ob + lane] = a0 * inv;
    out[ob + 64 + lane] = a1 * inv;
}

// ---------- fallback path (small ws): fp32 rope + round-2 kernel ----------
__global__ void rope_prep(const float* __restrict__ q, const float* __restrict__ k,
                          float* __restrict__ rq, float* __restrict__ rk) {
    int idx = blockIdx.x * blockDim.x + threadIdx.x;
    const int total = BATCH * SEQ * (DM / 2);
    if (idx >= total) return;
    int i   = idx & 63;
    int pos = (idx >> 6) & (SEQ - 1);
    int b   = idx >> 18;
    float dv  = powf(10000.0f, (float)(2 * i) / (float)DM);
    float ang = (float)pos / dv;
    float sn, cs;
    sincosf(ang, &sn, &cs);
    size_t base = ((size_t)b * SEQ + pos) * DM + 2 * i;
    float qe = q[base], qo = q[base + 1];
    float ke = k[base], ko = k[base + 1];
    rq[base]     = qe * cs - qo * sn;
    rq[base + 1] = qe * sn + qo * cs;
    rk[base]     = ke * cs - ko * sn;
    rk[base + 1] = ke * sn + ko * cs;
}

__launch_bounds__(256)
__global__ void topk_attn(const float* __restrict__ rq, const float* __restrict__ rk,
                          const float* __restrict__ v, float* __restrict__ out) {
    __shared__ unsigned umap[SEQ];
    __shared__ float    qs[DM];
    __shared__ int      selIdx[TOPK];
    __shared__ float    selW[TOPK];
    __shared__ int      cnt;
    __shared__ float    redf[4];
    __shared__ int      redi[4];
    __shared__ float    sMax, sSum;

    const int t   = blockIdx.x & (SEQ - 1);
    const int b   = blockIdx.x >> 12;
    const int tid = threadIdx.x;
    const int lane = tid & 63, wid = tid >> 6;
    const int n = t + 1;

    if (tid < DM) qs[tid] = rq[((size_t)b * SEQ + t) * DM + tid];
    if (tid == 0) cnt = 0;
    __syncthreads();

    float lmax = -INFINITY;
    for (int s = tid; s < n; s += 256) {
        const float4* kr = (const float4*)(rk + ((size_t)b * SEQ + s) * DM);
        const float4* qr = (const float4*)qs;
        float acc = 0.f;
        #pragma unroll
        for (int d = 0; d < DM / 4; ++d) {
            float4 kv = kr[d]; float4 qv = qr[d];
            acc += kv.x * qv.x + kv.y * qv.y + kv.z * qv.z + kv.w * qv.w;
        }
        float lgv = acc * SCALE;
        umap[s] = fmap(lgv);
        lmax = fmaxf(lmax, lgv);
    }
    #pragma unroll
    for (int off = 32; off; off >>= 1) lmax = fmaxf(lmax, __shfl_down(lmax, off));
    if (lane == 0) redf[wid] = lmax;
    __syncthreads();
    if (tid == 0) sMax = fmaxf(fmaxf(redf[0], redf[1]), fmaxf(redf[2], redf[3]));
    __syncthreads();
    const float M = sMax;

    const int K = (n < TOPK) ? n : TOPK;
    unsigned thr = 0u;
    if (n > TOPK) {
        unsigned long long lo = 0ull, hi = (unsigned long long)fmap(M);
        while (lo < hi) {
            unsigned long long mid = (lo + hi + 1ull) >> 1;
            unsigned m32 = (unsigned)mid;
            int c = 0;
            for (int s = tid; s < n; s += 256) c += (umap[s] >= m32) ? 1 : 0;
            #pragma unroll
            for (int off = 32; off; off >>= 1) c += __shfl_down(c, off);
            if (lane == 0) redi[wid] = c;
            __syncthreads();
            int tot = redi[0] + redi[1] + redi[2] + redi[3];
            __syncthreads();
            if (tot >= K) lo = mid; else hi = mid - 1ull;
        }
        thr = (unsigned)lo;
    }

    for (int s = tid; s < n; s += 256) {
        if (umap[s] > thr) {
            int p = atomicAdd(&cnt, 1);
            if (p < TOPK) { selIdx[p] = s; selW[p] = expf(finv(umap[s]) - M); }
        }
    }
    __syncthreads();
    for (int s = tid; s < n; s += 256) {
        if (umap[s] == thr) {
            int p = atomicAdd(&cnt, 1);
            if (p < TOPK) { selIdx[p] = s; selW[p] = expf(finv(umap[s]) - M); }
        }
    }
    __syncthreads();
    const int nsel = (cnt < TOPK) ? cnt : TOPK;

    if (tid < 64) {
        float w = (tid < nsel) ? selW[tid] : 0.f;
        #pragma unroll
        for (int off = 32; off; off >>= 1) w += __shfl_down(w, off);
        if (tid == 0) sSum = w;
    }
    __syncthreads();
    const float inv = 1.0f / sSum;

    if (tid < DM) {
        float a = 0.f;
        for (int j = 0; j < nsel; ++j)
            a += selW[j] * v[((size_t)b * SEQ + selIdx[j]) * DM + tid];
        out[((size_t)b * SEQ + t) * DM + tid] = a * inv;
    }
}

extern "C" void kernel_launch(void* const* d_in, const int* in_sizes, int n_in,
                              void* d_out, int out_size, void* d_ws, size_t ws_size,
                              hipStream_t stream) {
    const float* q = (const float*)d_in[0];
    const float* k = (const float*)d_in[1];
    const float* v = (const float*)d_in[2];
    float* out = (float*)d_out;

    const size_t plane = (size_t)BATCH * SEQ * DM;
    const size_t planesBytes = 6 * plane * sizeof(unsigned short);   // ~25 MB

    // plan 128-granular query-row chunks; cap chunk lgbuf at 96 MB (L3-resident)
    long long Wb = (long long)ws_size - (long long)planesBytes;
    const long long CAPB = 96ll << 20;
    int cr0[64], cm[64], nch = 0;
    bool ok = (Wb > 0);
    int r0 = 0;
    while (ok && r0 < SEQ) {
        int m = SEQ - r0;
        while (m >= 128) {
            long long stride = ((r0 + m + 127) / 128) * 128;
            long long bytes = (long long)BATCH * m * stride * 4;
            if (bytes <= Wb && bytes <= CAPB) break;
            m -= 128;
        }
        if (m < 128 || nch >= 64) { ok = false; break; }
        cr0[nch] = r0; cm[nch] = m; ++nch;
        r0 += m;
    }

    const int total = BATCH * SEQ * (DM / 2);

    if (!ok) {   // small-ws fallback: fp32 rope + round-2 kernel (needs 16 MB)
        float* rq = (float*)d_ws;
        float* rk = rq + plane;
        hipLaunchKernelGGL(rope_prep, dim3((total + 255) / 256), dim3(256), 0, stream,
                           q, k, rq, rk);
        hipLaunchKernelGGL(topk_attn, dim3(BATCH * SEQ), dim3(256), 0, stream,
                           rq, rk, v, out);
        return;
    }

    unsigned short* qh = (unsigned short*)d_ws;
    unsigned short* qm = qh + plane;
    unsigned short* ql = qm + plane;
    unsigned short* kh = ql + plane;
    unsigned short* km = kh + plane;
    unsigned short* kl = km + plane;
    float* lgbuf = (float*)((char*)d_ws + planesBytes);

    hipLaunchKernelGGL(rope_decomp, dim3((total + 255) / 256), dim3(256), 0, stream,
                       q, k, qh, qm, ql, kh, km, kl);

    for (int c = 0; c < nch; ++c) {
        const int R0 = cr0[c], M = cm[c];
        const int stride = ((R0 + M + 127) / 128) * 128;
        dim3 g1((R0 + M + 127) / 128, M / 128, BATCH);
        hipLaunchKernelGGL(logits_mfma, g1, dim3(256), 0, stream,
                           qh, qm, ql, kh, km, kl, lgbuf, R0, M, stride);
        dim3 g2((M + 3) / 4, BATCH);
        hipLaunchKernelGGL(select_out2, g2, dim3(256), 0, stream,
                           lgbuf, v, out, R0, M, stride);
    }
}